// Round 3
// baseline (424.768 us; speedup 1.0000x reference)
//
#include <hip/hip_runtime.h>

// ScaledDotProductAttention fwd: out0 = attn output [2,16,2048,64] f32,
// out1 = attn weights [2,16,2048,2048] f32.
// Round 3: same barrier-free structure as round 2, but MFMA via the builtin
// (__builtin_amdgcn_mfma_f32_16x16x32_bf16) instead of raw inline asm — the
// backend's hazard recognizer cannot see through INLINEASM, so pass 2's
// pipelined global loads clobbered MFMA source regs mid-read (pass-2-only
// garbage, O was correct). Builtin = modeled register lifetimes.

typedef __attribute__((ext_vector_type(4))) float f32x4;
typedef __attribute__((ext_vector_type(8))) short s16x8;
typedef __attribute__((ext_vector_type(4))) unsigned short u16x4;

#define S_LEN 2048
#define D_DIM 64
#define H_NUM 16
#define B_NUM 2
#define NT    32   // S/64 k-tiles
#define SW    32   // mask words per row (S/64)

__device__ __forceinline__ int swz(int row, int colByte) {
  return row * 128 + (colByte ^ ((row & 7) << 4));
}

__device__ __forceinline__ unsigned short f2bf(float f) {  // RNE f32->bf16
  unsigned int x = __builtin_bit_cast(unsigned int, f);
  x = (x + 0x7FFFu + ((x >> 16) & 1u)) >> 16;
  return (unsigned short)x;
}

__device__ __forceinline__ f32x4 mfma16(f32x4 acc, s16x8 a, s16x8 b) {
  return __builtin_amdgcn_mfma_f32_16x16x32_bf16(a, b, acc, 0, 0, 0);
}

// ---------------- prep kernels ----------------

__global__ __launch_bounds__(256) void mask_pack_kernel(const int* __restrict__ m,
                                                        unsigned long long* __restrict__ bits) {
  const int total = B_NUM * S_LEN * S_LEN;     // 8388608
  const int step  = gridDim.x * blockDim.x;    // 262144 -> 32 uniform iters
  for (int i = blockIdx.x * blockDim.x + threadIdx.x; i < total; i += step) {
    unsigned long long b = __ballot(m[i] != 0);
    if ((threadIdx.x & 63) == 0) bits[i >> 6] = b;
  }
}

__global__ __launch_bounds__(256) void cvt_qk_kernel(const float* __restrict__ Q,
                                                     const float* __restrict__ K,
                                                     u16x4* __restrict__ Q16,
                                                     u16x4* __restrict__ K16) {
  const int n4 = B_NUM * H_NUM * S_LEN * D_DIM / 4;  // 1048576
  const int step = gridDim.x * blockDim.x;
  for (int i = blockIdx.x * blockDim.x + threadIdx.x; i < n4; i += step) {
    float4 q = ((const float4*)Q)[i];
    Q16[i] = u16x4{f2bf(q.x), f2bf(q.y), f2bf(q.z), f2bf(q.w)};
    float4 k = ((const float4*)K)[i];
    K16[i] = u16x4{f2bf(k.x), f2bf(k.y), f2bf(k.z), f2bf(k.w)};
  }
}

__global__ __launch_bounds__(256) void v_transpose_kernel(const float* __restrict__ V,
                                                          unsigned short* __restrict__ VT) {
  __shared__ unsigned short t[64][72];
  const int bh = blockIdx.x >> 5;   // grid 1024
  const int st = blockIdx.x & 31;
  const float* src = V + ((size_t)bh * S_LEN + st * 64) * D_DIM;
  const int r0 = threadIdx.x >> 4;
  const int c  = (threadIdx.x & 15) * 4;
#pragma unroll
  for (int i = 0; i < 4; ++i) {
    const int r = r0 + i * 16;
    float4 v = *(const float4*)(src + r * D_DIM + c);
    t[c + 0][r] = f2bf(v.x); t[c + 1][r] = f2bf(v.y);
    t[c + 2][r] = f2bf(v.z); t[c + 3][r] = f2bf(v.w);
  }
  __syncthreads();
#pragma unroll
  for (int i = 0; i < 4; ++i) {
    const int idx = threadIdx.x + i * 256;
    const int d = idx >> 4;
    const int s4 = (idx & 15) * 4;
    u16x4 o = {t[d][s4], t[d][s4 + 1], t[d][s4 + 2], t[d][s4 + 3]};
    *(u16x4*)(VT + ((size_t)bh * D_DIM + d) * S_LEN + st * 64 + s4) = o;
  }
}

// ---------------- main kernel (barrier-free) ----------------

__global__ __launch_bounds__(256) void attn_main_kernel(
    const unsigned short* __restrict__ Q16, const unsigned short* __restrict__ K16,
    const unsigned short* __restrict__ VT16, const unsigned long long* __restrict__ Mb,
    float* __restrict__ Op, float* __restrict__ Wp)
{
  const int tid  = threadIdx.x;
  const int lane = tid & 63;
  const int wv   = tid >> 6;
  const int l15  = lane & 15;
  const int g4   = lane >> 4;

  // Bijective XCD swizzle (1024 % 8 == 0); qt-fastest so the 4 bh values per
  // XCD keep Q16/K16/VT16 (3 MB) resident in that XCD's 4 MB L2.
  const int wg = blockIdx.x;
  const int lg = (wg & 7) * 128 + (wg >> 3);
  const int qt = lg & 31;
  const int bh = lg >> 5;
  const int b  = bh >> 4;

  __shared__ __align__(16) char PsAll[4 * 2 * 2048];  // per-wave double-buffered P
  char* Ps0 = PsAll + (wv << 12);

  const unsigned short* Qg = Q16 + ((size_t)bh * S_LEN + qt * 64 + wv * 16 + l15) * D_DIM + g4 * 8;
  const unsigned short* Kg = K16 + (size_t)bh * S_LEN * D_DIM;
  const unsigned short* Vg = VT16 + (size_t)bh * D_DIM * S_LEN;
  float* Og = Op + ((size_t)bh * S_LEN + qt * 64) * D_DIM;
  float* Wg = Wp + ((size_t)bh * S_LEN + qt * 64) * S_LEN;
  const unsigned long long* Mg = Mb + ((size_t)b * S_LEN + qt * 64) * SW;

  const s16x8 qa0 = *(const s16x8*)Qg;
  const s16x8 qa1 = *(const s16x8*)(Qg + 32);

  f32x4 oacc[4];
#pragma unroll
  for (int i = 0; i < 4; ++i) oacc[i] = f32x4{0.f, 0.f, 0.f, 0.f};
  float lp[4] = {0.f, 0.f, 0.f, 0.f};

  const int qrow = wv * 16 + g4 * 4;

  // ================= PASS 1: rowsum + O accumulate =================
  for (int kt = 0; kt < NT; ++kt) {
    char* Ps = Ps0 + ((kt & 1) << 11);

    f32x4 sacc[4];
#pragma unroll
    for (int i = 0; i < 4; ++i) sacc[i] = f32x4{0.f, 0.f, 0.f, 0.f};
#pragma unroll
    for (int ct = 0; ct < 4; ++ct) {
      const unsigned short* kp = Kg + (size_t)(kt * 64 + ct * 16 + l15) * D_DIM + g4 * 8;
      s16x8 b0 = *(const s16x8*)kp;
      s16x8 b1 = *(const s16x8*)(kp + 32);
      sacc[ct] = mfma16(sacc[ct], qa0, b0);
      sacc[ct] = mfma16(sacc[ct], qa1, b1);
    }

    unsigned long long mw[4];
#pragma unroll
    for (int r = 0; r < 4; ++r) mw[r] = Mg[(qrow + r) * SW + kt];

#pragma unroll
    for (int ct = 0; ct < 4; ++ct) {
#pragma unroll
      for (int r = 0; r < 4; ++r) {
        float e = __expf(sacc[ct][r] * 0.125f);
        e = ((mw[r] >> (ct * 16 + l15)) & 1ull) ? e : 0.f;
        lp[r] += e;
        *(unsigned short*)(Ps + swz(g4 * 4 + r, (ct * 16 + l15) * 2)) = f2bf(e);
      }
    }
    // wave-internal cross-lane LDS hazard: drain DS queue, pin reads after
    asm volatile("s_waitcnt lgkmcnt(0)" ::: "memory");
    __builtin_amdgcn_sched_barrier(0);

    const s16x8 pa0 = *(const s16x8*)(Ps + swz(l15, g4 * 16));
    const s16x8 pa1 = *(const s16x8*)(Ps + swz(l15, g4 * 16 + 64));
#pragma unroll
    for (int ct = 0; ct < 4; ++ct) {
      const unsigned short* vp = Vg + (size_t)(ct * 16 + l15) * S_LEN + kt * 64 + g4 * 8;
      s16x8 v0 = *(const s16x8*)vp;
      s16x8 v1 = *(const s16x8*)(vp + 32);
      oacc[ct] = mfma16(oacc[ct], pa0, v0);
      oacc[ct] = mfma16(oacc[ct], pa1, v1);
    }
  }

  // rowsum reduce across the 16-lane column group; keep reciprocal
#pragma unroll
  for (int r = 0; r < 4; ++r) {
    float v = lp[r];
    v += __shfl_xor(v, 1);
    v += __shfl_xor(v, 2);
    v += __shfl_xor(v, 4);
    v += __shfl_xor(v, 8);
    lp[r] = 1.0f / v;
  }

#pragma unroll
  for (int ct = 0; ct < 4; ++ct)
#pragma unroll
    for (int r = 0; r < 4; ++r)
      Og[(size_t)(qrow + r) * D_DIM + ct * 16 + l15] = oacc[ct][r] * lp[r];

  // ================= PASS 2: recompute scores, stream weights =================
  for (int kt = 0; kt < NT; ++kt) {
    f32x4 sacc[4];
#pragma unroll
    for (int i = 0; i < 4; ++i) sacc[i] = f32x4{0.f, 0.f, 0.f, 0.f};
#pragma unroll
    for (int ct = 0; ct < 4; ++ct) {
      const unsigned short* kp = Kg + (size_t)(kt * 64 + ct * 16 + l15) * D_DIM + g4 * 8;
      s16x8 b0 = *(const s16x8*)kp;
      s16x8 b1 = *(const s16x8*)(kp + 32);
      sacc[ct] = mfma16(sacc[ct], qa0, b0);
      sacc[ct] = mfma16(sacc[ct], qa1, b1);
    }

    unsigned long long mw[4];
#pragma unroll
    for (int r = 0; r < 4; ++r) mw[r] = Mg[(qrow + r) * SW + kt];

#pragma unroll
    for (int ct = 0; ct < 4; ++ct) {
#pragma unroll
      for (int r = 0; r < 4; ++r) {
        float e = __expf(sacc[ct][r] * 0.125f);
        e = ((mw[r] >> (ct * 16 + l15)) & 1ull) ? e : 0.f;
        __builtin_nontemporal_store(e * lp[r],
            Wg + (size_t)(qrow + r) * S_LEN + kt * 64 + ct * 16 + l15);
      }
    }
  }
}

// ---------------- fallback (LDS-staged, barriered) ----------------

template <int USE_BITS>
__global__ __launch_bounds__(256) void attn_fwd_kernel(
    const float* __restrict__ Qp, const float* __restrict__ Kp, const float* __restrict__ Vp,
    const unsigned long long* __restrict__ Mb, const int* __restrict__ Mi,
    float* __restrict__ Op, float* __restrict__ Wp)
{
  const int tid  = threadIdx.x;
  const int lane = tid & 63;
  const int wv   = tid >> 6;
  const int l15  = lane & 15;
  const int g4   = lane >> 4;

  const int wg = blockIdx.x;
  const int lg = (wg & 7) * 128 + (wg >> 3);
  const int qt = lg & 31;
  const int bh = lg >> 5;
  const int b  = bh >> 4;

  __shared__ __align__(16) char lds[32768];
  char* Qs  = lds;
  char* Ks  = lds + 8192;
  char* VTs = lds + 16384;
  char* Ps  = lds + 24576 + (wv << 11);

  const float* Qg = Qp + ((size_t)bh * S_LEN + qt * 64) * D_DIM;
  const float* Kg = Kp + (size_t)bh * S_LEN * D_DIM;
  const float* Vg = Vp + (size_t)bh * S_LEN * D_DIM;
  float* Og = Op + ((size_t)bh * S_LEN + qt * 64) * D_DIM;
  float* Wg = Wp + ((size_t)bh * S_LEN + qt * 64) * S_LEN;
  const unsigned long long* Mg = Mb + ((size_t)b * S_LEN + qt * 64) * SW;
  const int* Mig = Mi + ((size_t)b * S_LEN + qt * 64) * S_LEN;

  {
    const int r0 = tid >> 4;
    const int c  = (tid & 15) * 4;
#pragma unroll
    for (int i = 0; i < 4; ++i) {
      const int r = r0 + i * 16;
      float4 v = *(const float4*)(Qg + r * D_DIM + c);
      ushort4 p; p.x = f2bf(v.x); p.y = f2bf(v.y); p.z = f2bf(v.z); p.w = f2bf(v.w);
      *(ushort4*)(Qs + swz(r, c * 2)) = p;
    }
  }
  __syncthreads();
  const s16x8 qa0 = *(const s16x8*)(Qs + swz(wv * 16 + l15, g4 * 16));
  const s16x8 qa1 = *(const s16x8*)(Qs + swz(wv * 16 + l15, g4 * 16 + 64));

  f32x4 oacc[4];
#pragma unroll
  for (int i = 0; i < 4; ++i) oacc[i] = f32x4{0.f, 0.f, 0.f, 0.f};
  float lp[4] = {0.f, 0.f, 0.f, 0.f};

  const int qrow = wv * 16 + g4 * 4;

  for (int kt = 0; kt < NT; ++kt) {
    __syncthreads();
    {
      const int r0 = tid >> 4;
      const int c  = (tid & 15) * 4;
      const float* Kt = Kg + kt * 64 * D_DIM;
#pragma unroll
      for (int i = 0; i < 4; ++i) {
        const int r = r0 + i * 16;
        float4 v = *(const float4*)(Kt + r * D_DIM + c);
        ushort4 p; p.x = f2bf(v.x); p.y = f2bf(v.y); p.z = f2bf(v.z); p.w = f2bf(v.w);
        *(ushort4*)(Ks + swz(r, c * 2)) = p;
      }
      const float* Vt = Vg + kt * 64 * D_DIM;
#pragma unroll
      for (int i = 0; i < 2; ++i) {
        const int rr = (tid >> 4) * 2 + i * 32;
        float4 a  = *(const float4*)(Vt + rr * D_DIM + c);
        float4 bq = *(const float4*)(Vt + (rr + 1) * D_DIM + c);
        const float av[4] = {a.x, a.y, a.z, a.w};
        const float bv[4] = {bq.x, bq.y, bq.z, bq.w};
#pragma unroll
        for (int j = 0; j < 4; ++j) {
          unsigned pk = (unsigned)f2bf(av[j]) | ((unsigned)f2bf(bv[j]) << 16);
          *(unsigned*)(VTs + swz(c + j, rr * 2)) = pk;
        }
      }
    }
    __syncthreads();

    unsigned long long mw[4] = {0, 0, 0, 0};
    if (USE_BITS) {
#pragma unroll
      for (int r = 0; r < 4; ++r) mw[r] = Mg[(qrow + r) * SW + kt];
    }

    f32x4 sacc[4];
#pragma unroll
    for (int i = 0; i < 4; ++i) sacc[i] = f32x4{0.f, 0.f, 0.f, 0.f};
#pragma unroll
    for (int ct = 0; ct < 4; ++ct) {
      s16x8 b0 = *(const s16x8*)(Ks + swz(ct * 16 + l15, g4 * 16));
      s16x8 b1 = *(const s16x8*)(Ks + swz(ct * 16 + l15, g4 * 16 + 64));
      sacc[ct] = mfma16(sacc[ct], qa0, b0);
      sacc[ct] = mfma16(sacc[ct], qa1, b1);
    }

#pragma unroll
    for (int ct = 0; ct < 4; ++ct) {
#pragma unroll
      for (int r = 0; r < 4; ++r) {
        float e = __expf(sacc[ct][r] * 0.125f);
        bool keep;
        if (USE_BITS) keep = (mw[r] >> (ct * 16 + l15)) & 1ull;
        else          keep = Mig[(size_t)(qrow + r) * S_LEN + kt * 64 + ct * 16 + l15] != 0;
        e = keep ? e : 0.f;
        lp[r] += e;
        *(unsigned short*)(Ps + swz(g4 * 4 + r, (ct * 16 + l15) * 2)) = f2bf(e);
      }
    }
    asm volatile("s_waitcnt lgkmcnt(0)" ::: "memory");
    __builtin_amdgcn_sched_barrier(0);

    const s16x8 pa0 = *(const s16x8*)(Ps + swz(l15, g4 * 16));
    const s16x8 pa1 = *(const s16x8*)(Ps + swz(l15, g4 * 16 + 64));
#pragma unroll
    for (int ct = 0; ct < 4; ++ct) {
      s16x8 v0 = *(const s16x8*)(VTs + swz(ct * 16 + l15, g4 * 16));
      s16x8 v1 = *(const s16x8*)(VTs + swz(ct * 16 + l15, g4 * 16 + 64));
      oacc[ct] = mfma16(oacc[ct], pa0, v0);
      oacc[ct] = mfma16(oacc[ct], pa1, v1);
    }
  }

#pragma unroll
  for (int r = 0; r < 4; ++r) {
    float v = lp[r];
    v += __shfl_xor(v, 1);
    v += __shfl_xor(v, 2);
    v += __shfl_xor(v, 4);
    v += __shfl_xor(v, 8);
    lp[r] = 1.0f / v;
  }

#pragma unroll
  for (int ct = 0; ct < 4; ++ct)
#pragma unroll
    for (int r = 0; r < 4; ++r)
      Og[(size_t)(qrow + r) * D_DIM + ct * 16 + l15] = oacc[ct][r] * lp[r];

  for (int kt = 0; kt < NT; ++kt) {
    __syncthreads();
    {
      const int r0 = tid >> 4;
      const int c  = (tid & 15) * 4;
      const float* Kt = Kg + kt * 64 * D_DIM;
#pragma unroll
      for (int i = 0; i < 4; ++i) {
        const int r = r0 + i * 16;
        float4 v = *(const float4*)(Kt + r * D_DIM + c);
        ushort4 p; p.x = f2bf(v.x); p.y = f2bf(v.y); p.z = f2bf(v.z); p.w = f2bf(v.w);
        *(ushort4*)(Ks + swz(r, c * 2)) = p;
      }
    }
    __syncthreads();

    unsigned long long mw[4] = {0, 0, 0, 0};
    if (USE_BITS) {
#pragma unroll
      for (int r = 0; r < 4; ++r) mw[r] = Mg[(qrow + r) * SW + kt];
    }

    f32x4 sacc[4];
#pragma unroll
    for (int i = 0; i < 4; ++i) sacc[i] = f32x4{0.f, 0.f, 0.f, 0.f};
#pragma unroll
    for (int ct = 0; ct < 4; ++ct) {
      s16x8 b0 = *(const s16x8*)(Ks + swz(ct * 16 + l15, g4 * 16));
      s16x8 b1 = *(const s16x8*)(Ks + swz(ct * 16 + l15, g4 * 16 + 64));
      sacc[ct] = mfma16(sacc[ct], qa0, b0);
      sacc[ct] = mfma16(sacc[ct], qa1, b1);
    }

#pragma unroll
    for (int ct = 0; ct < 4; ++ct) {
#pragma unroll
      for (int r = 0; r < 4; ++r) {
        float e = __expf(sacc[ct][r] * 0.125f);
        bool keep;
        if (USE_BITS) keep = (mw[r] >> (ct * 16 + l15)) & 1ull;
        else          keep = Mig[(size_t)(qrow + r) * S_LEN + kt * 64 + ct * 16 + l15] != 0;
        e = keep ? e : 0.f;
        __builtin_nontemporal_store(e * lp[r],
            Wg + (size_t)(qrow + r) * S_LEN + kt * 64 + ct * 16 + l15);
      }
    }
  }
}

extern "C" void kernel_launch(void* const* d_in, const int* in_sizes, int n_in,
                              void* d_out, int out_size, void* d_ws, size_t ws_size,
                              hipStream_t stream) {
  (void)in_sizes; (void)n_in; (void)out_size;
  const float* Q   = (const float*)d_in[0];
  const float* K   = (const float*)d_in[1];
  const float* V   = (const float*)d_in[2];
  const int* mask  = (const int*)d_in[3];
  float* Out = (float*)d_out;
  float* W   = Out + (size_t)B_NUM * H_NUM * S_LEN * D_DIM;

  const size_t bits_bytes = (size_t)(B_NUM * S_LEN * S_LEN / 64) * 8;      // 1 MiB
  const size_t t16_bytes  = (size_t)B_NUM * H_NUM * S_LEN * D_DIM * 2;     // 8 MiB
  unsigned long long* bits = (unsigned long long*)d_ws;

  if (ws_size >= bits_bytes + 3 * t16_bytes) {
    unsigned short* Q16 = (unsigned short*)((char*)d_ws + bits_bytes);
    unsigned short* K16 = Q16 + t16_bytes / 2;
    unsigned short* VT  = K16 + t16_bytes / 2;
    mask_pack_kernel<<<1024, 256, 0, stream>>>(mask, bits);
    cvt_qk_kernel<<<2048, 256, 0, stream>>>(Q, K, (u16x4*)Q16, (u16x4*)K16);
    v_transpose_kernel<<<1024, 256, 0, stream>>>(V, VT);
    attn_main_kernel<<<1024, 256, 0, stream>>>(Q16, K16, VT, bits, Out, W);
  } else if (ws_size >= bits_bytes) {
    mask_pack_kernel<<<1024, 256, 0, stream>>>(mask, bits);
    attn_fwd_kernel<1><<<1024, 256, 0, stream>>>(Q, K, V, bits, mask, Out, W);
  } else {
    attn_fwd_kernel<0><<<1024, 256, 0, stream>>>(Q, K, V, bits, mask, Out, W);
  }
}